// Round 2
// baseline (210.595 us; speedup 1.0000x reference)
//
#include <hip/hip_runtime.h>

typedef __attribute__((ext_vector_type(8))) short bf16x8;
typedef __attribute__((ext_vector_type(4))) short bf16x4;
typedef __attribute__((ext_vector_type(4))) float f32x4;
typedef unsigned short ushort_t;

#define B_ 4
#define H_ 8
#define N_ 2048
#define D_ 512
#define MAXREL 199   // MAX_REL-1
#define LOG2E 1.4426950408889634f

__device__ __forceinline__ ushort_t f2bf(float f) {
    union { float f; unsigned u; } v; v.f = f;
    unsigned r = v.u + 0x7fffu + ((v.u >> 16) & 1u);
    return (ushort_t)(r >> 16);
}
__device__ __forceinline__ float bf2f(ushort_t u) {
    union { unsigned u; float f; } v; v.u = ((unsigned)u) << 16;
    return v.f;
}
__device__ __forceinline__ float fexp2(float x) {
#if __has_builtin(__builtin_amdgcn_exp2f)
    return __builtin_amdgcn_exp2f(x);
#else
    return __expf(x * 0.6931471805599453f);
#endif
}
__device__ __forceinline__ unsigned cvt_pk_bf16(float lo, float hi) {
    unsigned r;
    asm("v_cvt_pk_bf16_f32 %0, %1, %2" : "=v"(r) : "v"(lo), "v"(hi));
    return r;
}
// async global->LDS, 16B per lane; lds dest = wave-uniform base + lane*16
__device__ __forceinline__ void gl_lds16(const ushort_t* g, ushort_t* l) {
    __builtin_amdgcn_global_load_lds(
        (const __attribute__((address_space(1))) void*)g,
        (__attribute__((address_space(3))) void*)l,
        16, 0, 0);
}

// ---------------- fused prep: bias_pack | layernorm | wtrans(Wqkv) | wtrans(Wout) ----------------
#define PREP_BIAS  16384                    // (N*N)/256
#define PREP_LN    8192                     // B*N rows
#define PREP_WQ    768                      // (1536/32)*(512/32)
#define PREP_WO    256                      // (512/32)*(512/32)
__global__ __launch_bounds__(256) void prep_kernel(const float* __restrict__ x,
                                                   const float* __restrict__ gamma,
                                                   const float* __restrict__ beta,
                                                   ushort_t* __restrict__ xn,
                                                   const float* __restrict__ Wqkv,
                                                   ushort_t* __restrict__ WqkvT,
                                                   const float* __restrict__ Wout,
                                                   ushort_t* __restrict__ WoutT,
                                                   const float* __restrict__ rel,
                                                   const int* __restrict__ mask,
                                                   ushort_t* __restrict__ bp) {
    __shared__ float smem[32 * 33];
    const int blk = blockIdx.x;
    const int t = threadIdx.x;

    if (blk < PREP_BIAS) {
        // ---- bias+mask pack: plain [n][m] bf16, pre-scaled into log2 domain ----
        int idx = blk * 256 + t;   // n*2048 + m
        int n = idx >> 11, m = idx & 2047;
        int dl = n - m;
        dl = dl < -MAXREL ? -MAXREL : (dl > MAXREL ? MAXREL : dl);
        float v = (mask[idx] == 0) ? -1e9f : rel[dl + MAXREL] * LOG2E;
        bp[idx] = f2bf(v);
    } else if (blk < PREP_BIAS + PREP_LN) {
        // ---- LayerNorm row ----
        const int row = blk - PREP_BIAS;
        const float* xr = x + (size_t)row * D_;
        float v0 = xr[t];
        float v1 = xr[t + 256];
        float s = v0 + v1;
        for (int o = 32; o > 0; o >>= 1) s += __shfl_down(s, o);
        if ((t & 63) == 0) smem[t >> 6] = s;
        __syncthreads();
        float mu = (smem[0] + smem[1] + smem[2] + smem[3]) * (1.0f / D_);
        __syncthreads();
        float d0 = v0 - mu, d1 = v1 - mu;
        float s2 = d0 * d0 + d1 * d1;
        for (int o = 32; o > 0; o >>= 1) s2 += __shfl_down(s2, o);
        if ((t & 63) == 0) smem[t >> 6] = s2;
        __syncthreads();
        float var = (smem[0] + smem[1] + smem[2] + smem[3]) * (1.0f / D_);
        float rs = rsqrtf(var + 1e-5f);
        ushort_t* yr = xn + (size_t)row * D_;
        yr[t]       = f2bf(d0 * rs * gamma[t]       + beta[t]);
        yr[t + 256] = f2bf(d1 * rs * gamma[t + 256] + beta[t + 256]);
    } else {
        // ---- weight transpose fp32 [K][Nn] -> bf16 [Nn][K] ----
        const float* W; ushort_t* Wt; int Nn, i;
        if (blk < PREP_BIAS + PREP_LN + PREP_WQ) {
            i = blk - (PREP_BIAS + PREP_LN); W = Wqkv; Wt = WqkvT; Nn = 1536;
        } else {
            i = blk - (PREP_BIAS + PREP_LN + PREP_WQ); W = Wout; Wt = WoutT; Nn = 512;
        }
        const int nb = Nn >> 5;
        const int bx = (i % nb) * 32, by = (i / nb) * 32;
        const int tx = t & 31, ty = t >> 5;
        float (*tile)[33] = (float(*)[33])smem;
        #pragma unroll
        for (int k = 0; k < 32; k += 8)
            tile[ty + k][tx] = W[(size_t)(by + ty + k) * Nn + bx + tx];
        __syncthreads();
        #pragma unroll
        for (int k = 0; k < 32; k += 8)
            Wt[(size_t)(bx + ty + k) * 512 + by + tx] = f2bf(tile[tx][ty + k]);
    }
}

// ---------------- QKV GEMM (MFMA bf16, global_load_lds staging): q scaled by 0.125*log2e ----------------
__global__ __launch_bounds__(256) void gemm_qkv(const ushort_t* __restrict__ A,
                                                const ushort_t* __restrict__ Bt,
                                                ushort_t* __restrict__ qb,
                                                ushort_t* __restrict__ kb,
                                                ushort_t* __restrict__ vb) {
    __shared__ ushort_t As[128 * 32];
    __shared__ ushort_t Bs[128 * 32];
    const int t = threadIdx.x;
    const int lane = t & 63, w = t >> 6;
    const int m16 = lane & 15, quad = lane >> 4;
    const int wr = w >> 1, wc = w & 1;
    const int r0 = blockIdx.y * 128, c0 = blockIdx.x * 128;

    const ushort_t* Ag = A  + (size_t)(r0 + (t >> 2)) * D_ + (t & 3) * 8;
    const ushort_t* Bg = Bt + (size_t)(c0 + (t >> 2)) * D_ + (t & 3) * 8;
    ushort_t* AsW = As + w * 512;
    ushort_t* BsW = Bs + w * 512;

    f32x4 acc[4][4];
    #pragma unroll
    for (int i = 0; i < 4; i++)
        #pragma unroll
        for (int j = 0; j < 4; j++) acc[i][j] = (f32x4){0.f, 0.f, 0.f, 0.f};

    for (int k0 = 0; k0 < D_; k0 += 32) {
        gl_lds16(Ag + k0, AsW);
        gl_lds16(Ag + k0 + (size_t)64 * D_, AsW + 2048);
        gl_lds16(Bg + k0, BsW);
        gl_lds16(Bg + k0 + (size_t)64 * D_, BsW + 2048);
        __syncthreads();
        bf16x8 af[4], bfr[4];
        #pragma unroll
        for (int rt = 0; rt < 4; rt++)
            af[rt] = *(const bf16x8*)(As + (wr * 64 + rt * 16 + m16) * 32 + quad * 8);
        #pragma unroll
        for (int ct = 0; ct < 4; ct++)
            bfr[ct] = *(const bf16x8*)(Bs + (wc * 64 + ct * 16 + m16) * 32 + quad * 8);
        #pragma unroll
        for (int rt = 0; rt < 4; rt++)
            #pragma unroll
            for (int ct = 0; ct < 4; ct++)
                acc[rt][ct] = __builtin_amdgcn_mfma_f32_16x16x32_bf16(af[rt], bfr[ct], acc[rt][ct], 0, 0, 0);
        __syncthreads();
    }

    #pragma unroll
    for (int ct = 0; ct < 4; ct++) {
        int cc = c0 + wc * 64 + ct * 16;      // 16-aligned, uniform per ct
        int which = cc >> 9;
        int h = (cc >> 6) & 7;
        int d = (cc & 63) + m16;
        #pragma unroll
        for (int rt = 0; rt < 4; rt++) {
            int rowb = r0 + wr * 64 + rt * 16 + quad * 4;
            int b = rowb >> 11, n0 = rowb & 2047;
            if (which == 0) {
                #pragma unroll
                for (int r = 0; r < 4; r++)
                    qb[((size_t)((b * H_ + h) * N_ + n0 + r)) * 64 + d] = f2bf(acc[rt][ct][r] * (0.125f * LOG2E));
            } else if (which == 1) {
                #pragma unroll
                for (int r = 0; r < 4; r++)
                    kb[((size_t)((b * H_ + h) * N_ + n0 + r)) * 64 + d] = f2bf(acc[rt][ct][r]);
            } else {
                union { ushort_t u4[4]; unsigned long long ll; } pk;
                #pragma unroll
                for (int r = 0; r < 4; r++) pk.u4[r] = f2bf(acc[rt][ct][r]);
                *(unsigned long long*)(vb + ((size_t)((b * H_ + h) * 64 + d)) * N_ + n0) = pk.ll;
            }
        }
    }
}

// ---------------- Out-proj (MFMA bf16, global_load_lds, BM=64) ----------------
__global__ __launch_bounds__(256) void gemm_out(const ushort_t* __restrict__ A,
                                                const ushort_t* __restrict__ Bt,
                                                const float* __restrict__ bias,
                                                float* __restrict__ C) {
    __shared__ ushort_t As[64 * 32];
    __shared__ ushort_t Bs[128 * 32];
    const int t = threadIdx.x;
    const int lane = t & 63, w = t >> 6;
    const int m16 = lane & 15, quad = lane >> 4;
    const int wr = w >> 1, wc = w & 1;        // wave tile: 32 rows x 64 cols
    const int r0 = blockIdx.y * 64, c0 = blockIdx.x * 128;

    const ushort_t* Ag = A  + (size_t)(r0 + (t >> 2)) * D_ + (t & 3) * 8;
    const ushort_t* Bg = Bt + (size_t)(c0 + (t >> 2)) * D_ + (t & 3) * 8;
    ushort_t* AsW = As + w * 512;
    ushort_t* BsW = Bs + w * 512;

    f32x4 acc[2][4];
    #pragma unroll
    for (int i = 0; i < 2; i++)
        #pragma unroll
        for (int j = 0; j < 4; j++) acc[i][j] = (f32x4){0.f, 0.f, 0.f, 0.f};

    for (int k0 = 0; k0 < D_; k0 += 32) {
        gl_lds16(Ag + k0, AsW);
        gl_lds16(Bg + k0, BsW);
        gl_lds16(Bg + k0 + (size_t)64 * D_, BsW + 2048);
        __syncthreads();
        bf16x8 af[2], bfr[4];
        #pragma unroll
        for (int mf = 0; mf < 2; mf++)
            af[mf] = *(const bf16x8*)(As + (wr * 32 + mf * 16 + m16) * 32 + quad * 8);
        #pragma unroll
        for (int nt = 0; nt < 4; nt++)
            bfr[nt] = *(const bf16x8*)(Bs + (wc * 64 + nt * 16 + m16) * 32 + quad * 8);
        #pragma unroll
        for (int mf = 0; mf < 2; mf++)
            #pragma unroll
            for (int nt = 0; nt < 4; nt++)
                acc[mf][nt] = __builtin_amdgcn_mfma_f32_16x16x32_bf16(af[mf], bfr[nt], acc[mf][nt], 0, 0, 0);
        __syncthreads();
    }

    #pragma unroll
    for (int mf = 0; mf < 2; mf++) {
        #pragma unroll
        for (int nt = 0; nt < 4; nt++) {
            int col = c0 + wc * 64 + nt * 16 + m16;
            int row0 = r0 + wr * 32 + mf * 16 + quad * 4;
            float bv = bias[col];
            #pragma unroll
            for (int r = 0; r < 4; r++)
                C[(size_t)(row0 + r) * 512 + col] = acc[mf][nt][r] + bv;
        }
    }
}

// ---------------- MFMA flash attention v7: swapped QK^T + shfl-based in-register P transpose ----------------
// mfma(K,Q) gives P[key=quad*4+r][qrow=m16] per lane. PV A-frag needs P[qrow=m16][key=quad*8+j].
// Movement (derived & lane-checked): pa.u[c] = sel(quad<2, shfl(pk_even(c), src), shfl(pk_odd(c), src))
// with src = m16 + 32*(quad&1) for c in {0,1} and src+16 for c in {2,3}.
// Bias pre-scaled by log2e, fed as MFMA acc-init; p = exp2(s). No P LDS round trip.
__global__ __launch_bounds__(512, 4) void attn_mfma(const ushort_t* __restrict__ qb,
                                                    const ushort_t* __restrict__ kb,
                                                    const ushort_t* __restrict__ vb,
                                                    const ushort_t* __restrict__ bp,
                                                    ushort_t* __restrict__ attn) {
    __shared__ ushort_t Ks[2][64 * 64];      // [buf][key][d] swizzled, 8KB each
    __shared__ ushort_t Vs[2][64 * 64];      // [buf][d][key] swizzled, 8KB each

    const int t = threadIdx.x;
    const int w = t >> 6, lane = t & 63;
    const int m16 = lane & 15, quad = lane >> 4;
    const int id = blockIdx.x;
    const int bh = id & 31;                  // XCD = id%8 = bh%8 (heuristic)
    const int qt = id >> 5;
    const int b = bh >> 3, h = bh & 7;
    const int n0w = qt * 128 + w * 16;

    // staging: thread stages exactly one 8-elem chunk of K and of V per tile
    const int srow = t >> 3, scb = t & 7;
    const int soff = srow * 64 + (scb ^ (srow & 7)) * 8;
    const ushort_t* kgbase = kb + ((size_t)bh * N_) * 64;   // [key][d]
    const ushort_t* vgbase = vb + ((size_t)bh * 64) * N_;   // [d][key]

    // Q frags (one 16-row m-frag per wave)
    const ushort_t* qpb = qb + ((size_t)(bh * N_ + n0w + m16)) * 64 + quad * 8;
    bf16x8 qa0 = *(const bf16x8*)(qpb);
    bf16x8 qa1 = *(const bf16x8*)(qpb + 32);

    // bias: plain [n][2048]; lane needs (qrow=m16, keys nt*16+quad*4..+3)
    const ushort_t* bprow = bp + (size_t)(n0w + m16) * 2048 + quad * 4;

    // P-transpose source lanes
    const int srcA = m16 + 32 * (quad & 1);
    const int srcB = srcA + 16;
    const bool lowhalf = (quad < 2);

    // prologue: stage tile 0 into buf 0
    *(bf16x8*)(&Ks[0][soff]) = *(const bf16x8*)(kgbase + (size_t)srow * 64 + scb * 8);
    *(bf16x8*)(&Vs[0][soff]) = *(const bf16x8*)(vgbase + (size_t)srow * N_ + scb * 8);
    __syncthreads();

    f32x4 o[4];
    #pragma unroll
    for (int nt = 0; nt < 4; nt++) o[nt] = (f32x4){0.f, 0.f, 0.f, 0.f};
    float rsum = 0.f;

    for (int jt = 0; jt < 32; jt++) {
        const int buf = jt & 1;
        const int j0 = jt * 64;
        const bool more = (jt < 31);

        // ---- issue global staging loads for next tile ----
        bf16x8 kst, vst;
        if (more) {
            kst = *(const bf16x8*)(kgbase + (size_t)(j0 + 64 + srow) * 64 + scb * 8);
            vst = *(const bf16x8*)(vgbase + (size_t)srow * N_ + j0 + 64 + scb * 8);
        }

        // ---- bias loads (acc-init values) ----
        bf16x4 bc[4];
        #pragma unroll
        for (int nt = 0; nt < 4; nt++) bc[nt] = *(const bf16x4*)(bprow + jt * 64 + nt * 16);

        // ---- swapped QK^T (D[key][qrow]) + exp2 + pack ----
        unsigned pk[8];
        #pragma unroll
        for (int nt = 0; nt < 4; nt++) {
            f32x4 a2;
            #pragma unroll
            for (int r = 0; r < 4; r++) a2[r] = bf2f((ushort_t)bc[nt][r]);
            int kr = nt * 16 + m16;
            bf16x8 kf0 = *(const bf16x8*)(&Ks[buf][kr * 64 + ((quad) ^ (kr & 7)) * 8]);
            bf16x8 kf1 = *(const bf16x8*)(&Ks[buf][kr * 64 + ((quad + 4) ^ (kr & 7)) * 8]);
            a2 = __builtin_amdgcn_mfma_f32_16x16x32_bf16(kf0, qa0, a2, 0, 0, 0);
            a2 = __builtin_amdgcn_mfma_f32_16x16x32_bf16(kf1, qa1, a2, 0, 0, 0);
            float p0 = fexp2(a2[0]);
            float p1 = fexp2(a2[1]);
            float p2 = fexp2(a2[2]);
            float p3 = fexp2(a2[3]);
            rsum += (p0 + p1) + (p2 + p3);
            pk[nt * 2]     = cvt_pk_bf16(p0, p1);
            pk[nt * 2 + 1] = cvt_pk_bf16(p2, p3);
        }

        // ---- in-register P transpose via shfl (ds_bpermute) + select ----
        union { unsigned u[4]; bf16x8 v; } pa0u, pa1u;
        {
            unsigned e0 = __shfl(pk[0], srcA), o0 = __shfl(pk[2], srcA);
            unsigned e1 = __shfl(pk[1], srcA), o1 = __shfl(pk[3], srcA);
            unsigned e2 = __shfl(pk[0], srcB), o2 = __shfl(pk[2], srcB);
            unsigned e3 = __shfl(pk[1], srcB), o3 = __shfl(pk[3], srcB);
            pa0u.u[0] = lowhalf ? e0 : o0;
            pa0u.u[1] = lowhalf ? e1 : o1;
            pa0u.u[2] = lowhalf ? e2 : o2;
            pa0u.u[3] = lowhalf ? e3 : o3;
            unsigned f0 = __shfl(pk[4], srcA), g0 = __shfl(pk[6], srcA);
            unsigned f1 = __shfl(pk[5], srcA), g1 = __shfl(pk[7], srcA);
            unsigned f2 = __shfl(pk[4], srcB), g2 = __shfl(pk[6], srcB);
            unsigned f3 = __shfl(pk[5], srcB), g3 = __shfl(pk[7], srcB);
            pa1u.u[0] = lowhalf ? f0 : g0;
            pa1u.u[1] = lowhalf ? f1 : g1;
            pa1u.u[2] = lowhalf ? f2 : g2;
            pa1u.u[3] = lowhalf ? f3 : g3;
        }

        // ---- V frags from LDS + P·V ----
        #pragma unroll
        for (int nt = 0; nt < 4; nt++) {
            int d = nt * 16 + m16;
            bf16x8 vf0 = *(const bf16x8*)(&Vs[buf][d * 64 + ((quad) ^ (d & 7)) * 8]);
            bf16x8 vf1 = *(const bf16x8*)(&Vs[buf][d * 64 + ((quad + 4) ^ (d & 7)) * 8]);
            o[nt] = __builtin_amdgcn_mfma_f32_16x16x32_bf16(pa0u.v, vf0, o[nt], 0, 0, 0);
            o[nt] = __builtin_amdgcn_mfma_f32_16x16x32_bf16(pa1u.v, vf1, o[nt], 0, 0, 0);
        }

        // ---- stage next tile into other buffer; one barrier per tile ----
        if (more) {
            *(bf16x8*)(&Ks[buf ^ 1][soff]) = kst;
            *(bf16x8*)(&Vs[buf ^ 1][soff]) = vst;
        }
        __syncthreads();
    }

    // ---- row-sum: lane holds partial for qrow=m16 over its 16 key-residues; reduce across quads ----
    rsum += __shfl_xor(rsum, 16);
    rsum += __shfl_xor(rsum, 32);

    // ---- normalize + store: o[nt][r] is (qrow=quad*4+r, d=nt*16+m16) ----
    #pragma unroll
    for (int r = 0; r < 4; r++) {
        float inv = 1.0f / __shfl(rsum, quad * 4 + r);
        int n = n0w + quad * 4 + r;
        ushort_t* orow = attn + ((size_t)(b * N_ + n)) * 512 + h * 64 + m16;
        #pragma unroll
        for (int nt = 0; nt < 4; nt++) orow[nt * 16] = f2bf(o[nt][r] * inv);
    }
}

extern "C" void kernel_launch(void* const* d_in, const int* in_sizes, int n_in,
                              void* d_out, int out_size, void* d_ws, size_t ws_size,
                              hipStream_t stream) {
    const float* x     = (const float*)d_in[0];
    const float* gamma = (const float*)d_in[1];
    const float* beta  = (const float*)d_in[2];
    const float* Wqkv  = (const float*)d_in[3];
    const float* Wout  = (const float*)d_in[4];
    const float* bout  = (const float*)d_in[5];
    const float* rel   = (const float*)d_in[6];
    const int*   mask  = (const int*)d_in[7];
    float* out = (float*)d_out;

    char* wsb = (char*)d_ws;
    ushort_t* xn    = (ushort_t*)(wsb);                    //  8 MB
    ushort_t* attnb = (ushort_t*)(wsb + ( 8u << 20));      //  8 MB
    ushort_t* qb    = (ushort_t*)(wsb + (16u << 20));      //  8 MB
    ushort_t* kb    = (ushort_t*)(wsb + (24u << 20));      //  8 MB
    ushort_t* vb    = (ushort_t*)(wsb + (32u << 20));      //  8 MB
    ushort_t* WqkvT = (ushort_t*)(wsb + (40u << 20));      //  1.5 MB
    ushort_t* WoutT = (ushort_t*)(wsb + (42u << 20));      //  0.5 MB
    ushort_t* bp    = (ushort_t*)(wsb + (44u << 20));      //  8 MB

    // 1. fused prep: bias_pack + layernorm + both weight transposes (one launch)
    prep_kernel<<<PREP_BIAS + PREP_LN + PREP_WQ + PREP_WO, 256, 0, stream>>>(
        x, gamma, beta, xn, Wqkv, WqkvT, Wout, WoutT, rel, mask, bp);

    // 2. QKV projection (MFMA + global_load_lds) -> bf16 q(scaled by 0.125*log2e)/k/v
    gemm_qkv<<<dim3(1536 / 128, 8192 / 128), 256, 0, stream>>>(xn, WqkvT, qb, kb, vb);

    // 3. MFMA flash attention v7 -> bf16
    attn_mfma<<<512, 512, 0, stream>>>(qb, kb, vb, bp, attnb);

    // 4. output projection + bias (MFMA + global_load_lds) -> fp32
    gemm_out<<<dim3(512 / 128, 8192 / 64), 256, 0, stream>>>(attnb, WoutT, bout, out);
}

// Round 3
// 200.397 us; speedup vs baseline: 1.0509x; 1.0509x over previous
//
#include <hip/hip_runtime.h>

typedef __attribute__((ext_vector_type(8))) short bf16x8;
typedef __attribute__((ext_vector_type(4))) short bf16x4;
typedef __attribute__((ext_vector_type(4))) float f32x4;
typedef unsigned short ushort_t;

#define B_ 4
#define H_ 8
#define N_ 2048
#define D_ 512
#define MAXREL 199   // MAX_REL-1
#define LOG2E 1.4426950408889634f

__device__ __forceinline__ ushort_t f2bf(float f) {
    union { float f; unsigned u; } v; v.f = f;
    unsigned r = v.u + 0x7fffu + ((v.u >> 16) & 1u);
    return (ushort_t)(r >> 16);
}
__device__ __forceinline__ float bf2f(ushort_t u) {
    union { unsigned u; float f; } v; v.u = ((unsigned)u) << 16;
    return v.f;
}
__device__ __forceinline__ float fexp2(float x) {
#if __has_builtin(__builtin_amdgcn_exp2f)
    return __builtin_amdgcn_exp2f(x);
#else
    return __expf(x * 0.6931471805599453f);
#endif
}
__device__ __forceinline__ unsigned cvt_pk_bf16(float lo, float hi) {
    unsigned r;
    asm("v_cvt_pk_bf16_f32 %0, %1, %2" : "=v"(r) : "v"(lo), "v"(hi));
    return r;
}
// async global->LDS, 16B per lane; lds dest = wave-uniform base + lane*16
__device__ __forceinline__ void gl_lds16(const ushort_t* g, ushort_t* l) {
    __builtin_amdgcn_global_load_lds(
        (const __attribute__((address_space(1))) void*)g,
        (__attribute__((address_space(3))) void*)l,
        16, 0, 0);
}

// ---------------- fused prep: bias_pack | layernorm | wtrans(Wqkv) | wtrans(Wout) ----------------
#define PREP_BIAS  16384                    // (N*N)/256
#define PREP_LN    8192                     // B*N rows
#define PREP_WQ    768                      // (1536/32)*(512/32)
#define PREP_WO    256                      // (512/32)*(512/32)
__global__ __launch_bounds__(256) void prep_kernel(const float* __restrict__ x,
                                                   const float* __restrict__ gamma,
                                                   const float* __restrict__ beta,
                                                   ushort_t* __restrict__ xn,
                                                   const float* __restrict__ Wqkv,
                                                   ushort_t* __restrict__ WqkvT,
                                                   const float* __restrict__ Wout,
                                                   ushort_t* __restrict__ WoutT,
                                                   const float* __restrict__ rel,
                                                   const int* __restrict__ mask,
                                                   ushort_t* __restrict__ bp) {
    __shared__ float smem[32 * 33];
    const int blk = blockIdx.x;
    const int t = threadIdx.x;

    if (blk < PREP_BIAS) {
        // ---- bias+mask pack into attn load order [qt][jt][w][nt][quad][m16][k4], log2 domain ----
        int idx = blk * 256 + t;   // n*2048 + m
        int n = idx >> 11, m = idx & 2047;
        int dl = n - m;
        dl = dl < -MAXREL ? -MAXREL : (dl > MAXREL ? MAXREL : dl);
        float v = (mask[idx] == 0) ? -1e9f : rel[dl + MAXREL] * LOG2E;
        // qrow = qt*128 + w*16 + m16 ; key = jt*64 + nt*16 + quad*4 + k4
        int off = ((n >> 7) << 18) + ((m >> 6) << 13) + (((n >> 4) & 7) << 10)
                + (((m >> 4) & 3) << 8) + (((m >> 2) & 3) << 6) + ((n & 15) << 2) + (m & 3);
        bp[off] = f2bf(v);
    } else if (blk < PREP_BIAS + PREP_LN) {
        // ---- LayerNorm row ----
        const int row = blk - PREP_BIAS;
        const float* xr = x + (size_t)row * D_;
        float v0 = xr[t];
        float v1 = xr[t + 256];
        float s = v0 + v1;
        for (int o = 32; o > 0; o >>= 1) s += __shfl_down(s, o);
        if ((t & 63) == 0) smem[t >> 6] = s;
        __syncthreads();
        float mu = (smem[0] + smem[1] + smem[2] + smem[3]) * (1.0f / D_);
        __syncthreads();
        float d0 = v0 - mu, d1 = v1 - mu;
        float s2 = d0 * d0 + d1 * d1;
        for (int o = 32; o > 0; o >>= 1) s2 += __shfl_down(s2, o);
        if ((t & 63) == 0) smem[t >> 6] = s2;
        __syncthreads();
        float var = (smem[0] + smem[1] + smem[2] + smem[3]) * (1.0f / D_);
        float rs = rsqrtf(var + 1e-5f);
        ushort_t* yr = xn + (size_t)row * D_;
        yr[t]       = f2bf(d0 * rs * gamma[t]       + beta[t]);
        yr[t + 256] = f2bf(d1 * rs * gamma[t + 256] + beta[t + 256]);
    } else {
        // ---- weight transpose fp32 [K][Nn] -> bf16 [Nn][K] ----
        const float* W; ushort_t* Wt; int Nn, i;
        if (blk < PREP_BIAS + PREP_LN + PREP_WQ) {
            i = blk - (PREP_BIAS + PREP_LN); W = Wqkv; Wt = WqkvT; Nn = 1536;
        } else {
            i = blk - (PREP_BIAS + PREP_LN + PREP_WQ); W = Wout; Wt = WoutT; Nn = 512;
        }
        const int nb = Nn >> 5;
        const int bx = (i % nb) * 32, by = (i / nb) * 32;
        const int tx = t & 31, ty = t >> 5;
        float (*tile)[33] = (float(*)[33])smem;
        #pragma unroll
        for (int k = 0; k < 32; k += 8)
            tile[ty + k][tx] = W[(size_t)(by + ty + k) * Nn + bx + tx];
        __syncthreads();
        #pragma unroll
        for (int k = 0; k < 32; k += 8)
            Wt[(size_t)(bx + ty + k) * 512 + by + tx] = f2bf(tile[tx][ty + k]);
    }
}

// ---------------- QKV GEMM (MFMA bf16, global_load_lds staging): q scaled by 0.125*log2e ----------------
__global__ __launch_bounds__(256) void gemm_qkv(const ushort_t* __restrict__ A,
                                                const ushort_t* __restrict__ Bt,
                                                ushort_t* __restrict__ qb,
                                                ushort_t* __restrict__ kb,
                                                ushort_t* __restrict__ vb) {
    __shared__ ushort_t As[128 * 32];
    __shared__ ushort_t Bs[128 * 32];
    const int t = threadIdx.x;
    const int lane = t & 63, w = t >> 6;
    const int m16 = lane & 15, quad = lane >> 4;
    const int wr = w >> 1, wc = w & 1;
    const int r0 = blockIdx.y * 128, c0 = blockIdx.x * 128;

    const ushort_t* Ag = A  + (size_t)(r0 + (t >> 2)) * D_ + (t & 3) * 8;
    const ushort_t* Bg = Bt + (size_t)(c0 + (t >> 2)) * D_ + (t & 3) * 8;
    ushort_t* AsW = As + w * 512;
    ushort_t* BsW = Bs + w * 512;

    f32x4 acc[4][4];
    #pragma unroll
    for (int i = 0; i < 4; i++)
        #pragma unroll
        for (int j = 0; j < 4; j++) acc[i][j] = (f32x4){0.f, 0.f, 0.f, 0.f};

    for (int k0 = 0; k0 < D_; k0 += 32) {
        gl_lds16(Ag + k0, AsW);
        gl_lds16(Ag + k0 + (size_t)64 * D_, AsW + 2048);
        gl_lds16(Bg + k0, BsW);
        gl_lds16(Bg + k0 + (size_t)64 * D_, BsW + 2048);
        __syncthreads();
        bf16x8 af[4], bfr[4];
        #pragma unroll
        for (int rt = 0; rt < 4; rt++)
            af[rt] = *(const bf16x8*)(As + (wr * 64 + rt * 16 + m16) * 32 + quad * 8);
        #pragma unroll
        for (int ct = 0; ct < 4; ct++)
            bfr[ct] = *(const bf16x8*)(Bs + (wc * 64 + ct * 16 + m16) * 32 + quad * 8);
        #pragma unroll
        for (int rt = 0; rt < 4; rt++)
            #pragma unroll
            for (int ct = 0; ct < 4; ct++)
                acc[rt][ct] = __builtin_amdgcn_mfma_f32_16x16x32_bf16(af[rt], bfr[ct], acc[rt][ct], 0, 0, 0);
        __syncthreads();
    }

    #pragma unroll
    for (int ct = 0; ct < 4; ct++) {
        int cc = c0 + wc * 64 + ct * 16;      // 16-aligned, uniform per ct
        int which = cc >> 9;
        int h = (cc >> 6) & 7;
        int d = (cc & 63) + m16;
        #pragma unroll
        for (int rt = 0; rt < 4; rt++) {
            int rowb = r0 + wr * 64 + rt * 16 + quad * 4;
            int b = rowb >> 11, n0 = rowb & 2047;
            if (which == 0) {
                #pragma unroll
                for (int r = 0; r < 4; r++)
                    qb[((size_t)((b * H_ + h) * N_ + n0 + r)) * 64 + d] = f2bf(acc[rt][ct][r] * (0.125f * LOG2E));
            } else if (which == 1) {
                #pragma unroll
                for (int r = 0; r < 4; r++)
                    kb[((size_t)((b * H_ + h) * N_ + n0 + r)) * 64 + d] = f2bf(acc[rt][ct][r]);
            } else {
                union { ushort_t u4[4]; unsigned long long ll; } pk;
                #pragma unroll
                for (int r = 0; r < 4; r++) pk.u4[r] = f2bf(acc[rt][ct][r]);
                *(unsigned long long*)(vb + ((size_t)((b * H_ + h) * 64 + d)) * N_ + n0) = pk.ll;
            }
        }
    }
}

// ---------------- Out-proj (MFMA bf16, global_load_lds, BM=64) ----------------
__global__ __launch_bounds__(256) void gemm_out(const ushort_t* __restrict__ A,
                                                const ushort_t* __restrict__ Bt,
                                                const float* __restrict__ bias,
                                                float* __restrict__ C) {
    __shared__ ushort_t As[64 * 32];
    __shared__ ushort_t Bs[128 * 32];
    const int t = threadIdx.x;
    const int lane = t & 63, w = t >> 6;
    const int m16 = lane & 15, quad = lane >> 4;
    const int wr = w >> 1, wc = w & 1;        // wave tile: 32 rows x 64 cols
    const int r0 = blockIdx.y * 64, c0 = blockIdx.x * 128;

    const ushort_t* Ag = A  + (size_t)(r0 + (t >> 2)) * D_ + (t & 3) * 8;
    const ushort_t* Bg = Bt + (size_t)(c0 + (t >> 2)) * D_ + (t & 3) * 8;
    ushort_t* AsW = As + w * 512;
    ushort_t* BsW = Bs + w * 512;

    f32x4 acc[2][4];
    #pragma unroll
    for (int i = 0; i < 2; i++)
        #pragma unroll
        for (int j = 0; j < 4; j++) acc[i][j] = (f32x4){0.f, 0.f, 0.f, 0.f};

    for (int k0 = 0; k0 < D_; k0 += 32) {
        gl_lds16(Ag + k0, AsW);
        gl_lds16(Bg + k0, BsW);
        gl_lds16(Bg + k0 + (size_t)64 * D_, BsW + 2048);
        __syncthreads();
        bf16x8 af[2], bfr[4];
        #pragma unroll
        for (int mf = 0; mf < 2; mf++)
            af[mf] = *(const bf16x8*)(As + (wr * 32 + mf * 16 + m16) * 32 + quad * 8);
        #pragma unroll
        for (int nt = 0; nt < 4; nt++)
            bfr[nt] = *(const bf16x8*)(Bs + (wc * 64 + nt * 16 + m16) * 32 + quad * 8);
        #pragma unroll
        for (int mf = 0; mf < 2; mf++)
            #pragma unroll
            for (int nt = 0; nt < 4; nt++)
                acc[mf][nt] = __builtin_amdgcn_mfma_f32_16x16x32_bf16(af[mf], bfr[nt], acc[mf][nt], 0, 0, 0);
        __syncthreads();
    }

    #pragma unroll
    for (int mf = 0; mf < 2; mf++) {
        #pragma unroll
        for (int nt = 0; nt < 4; nt++) {
            int col = c0 + wc * 64 + nt * 16 + m16;
            int row0 = r0 + wr * 32 + mf * 16 + quad * 4;
            float bv = bias[col];
            #pragma unroll
            for (int r = 0; r < 4; r++)
                C[(size_t)(row0 + r) * 512 + col] = acc[mf][nt][r] + bv;
        }
    }
}

// ---------------- MFMA flash attention v8: swapped QK^T + pair-packed LDS P round-trip ----------------
// mfma(K,Q) gives P^T(key=nt*16+quad*4+r, qrow=m16) per lane. cvt_pk pairs adjacent keys;
// 8x ds_write_b32 into per-wave [qrow][key] chunk-XOR-swizzled buffer (phase-conflict-free),
// 2x ds_read_b128 recover the PV A-frags (round-0 verified read pattern).
// Bias pre-scaled by log2e, packed in load order, fed as MFMA acc-init; p = exp2(s).
__global__ __launch_bounds__(512, 4) void attn_mfma(const ushort_t* __restrict__ qb,
                                                    const ushort_t* __restrict__ kb,
                                                    const ushort_t* __restrict__ vb,
                                                    const ushort_t* __restrict__ bp,
                                                    ushort_t* __restrict__ attn) {
    __shared__ ushort_t Ks[2][64 * 64];      // [buf][key][d] swizzled, 8KB each
    __shared__ ushort_t Vs[2][64 * 64];      // [buf][d][key] swizzled, 8KB each
    __shared__ ushort_t p_s[8][16 * 64];     // [wave][qrow][key] swizzled, 16KB

    const int t = threadIdx.x;
    const int w = t >> 6, lane = t & 63;
    const int m16 = lane & 15, quad = lane >> 4;
    const int id = blockIdx.x;
    const int bh = id & 31;                  // XCD = id%8 = bh%8 (heuristic)
    const int qt = id >> 5;
    const int b = bh >> 3, h = bh & 7;
    const int n0w = qt * 128 + w * 16;

    // staging: thread stages exactly one 8-elem chunk of K and of V per tile
    const int srow = t >> 3, scb = t & 7;
    const int soff = srow * 64 + (scb ^ (srow & 7)) * 8;
    const ushort_t* kgbase = kb + ((size_t)bh * N_) * 64;   // [key][d]
    const ushort_t* vgbase = vb + ((size_t)bh * 64) * N_;   // [d][key]

    // Q frags (one 16-row m-frag per wave)
    const ushort_t* qpb = qb + ((size_t)(bh * N_ + n0w + m16)) * 64 + quad * 8;
    bf16x8 qa0 = *(const bf16x8*)(qpb);
    bf16x8 qa1 = *(const bf16x8*)(qpb + 32);

    // bias packed [qt][jt][w][nt][quad][m16][k4]; per phase the 16 m16-lanes read 128B contiguous
    const ushort_t* bpb = bp + ((size_t)qt << 18) + (w << 10) + (quad << 6) + (m16 << 2);

    // prologue: stage tile 0 into buf 0
    *(bf16x8*)(&Ks[0][soff]) = *(const bf16x8*)(kgbase + (size_t)srow * 64 + scb * 8);
    *(bf16x8*)(&Vs[0][soff]) = *(const bf16x8*)(vgbase + (size_t)srow * N_ + scb * 8);
    __syncthreads();

    f32x4 o[4];
    #pragma unroll
    for (int nt = 0; nt < 4; nt++) o[nt] = (f32x4){0.f, 0.f, 0.f, 0.f};
    float rsum = 0.f;

    ushort_t* pw = p_s[w];

    for (int jt = 0; jt < 32; jt++) {
        const int buf = jt & 1;
        const int j0 = jt * 64;
        const bool more = (jt < 31);

        // ---- issue global staging loads for next tile ----
        bf16x8 kst, vst;
        if (more) {
            kst = *(const bf16x8*)(kgbase + (size_t)(j0 + 64 + srow) * 64 + scb * 8);
            vst = *(const bf16x8*)(vgbase + (size_t)srow * N_ + j0 + 64 + scb * 8);
        }

        // ---- bias loads (acc-init values) ----
        bf16x4 bc[4];
        #pragma unroll
        for (int nt = 0; nt < 4; nt++) bc[nt] = *(const bf16x4*)(bpb + (jt << 13) + (nt << 8));

        // ---- swapped QK^T (D[key][qrow]) + exp2 + pack ----
        unsigned pk[8];
        #pragma unroll
        for (int nt = 0; nt < 4; nt++) {
            f32x4 a2;
            #pragma unroll
            for (int r = 0; r < 4; r++) a2[r] = bf2f((ushort_t)bc[nt][r]);
            int kr = nt * 16 + m16;
            bf16x8 kf0 = *(const bf16x8*)(&Ks[buf][kr * 64 + ((quad) ^ (kr & 7)) * 8]);
            bf16x8 kf1 = *(const bf16x8*)(&Ks[buf][kr * 64 + ((quad + 4) ^ (kr & 7)) * 8]);
            a2 = __builtin_amdgcn_mfma_f32_16x16x32_bf16(kf0, qa0, a2, 0, 0, 0);
            a2 = __builtin_amdgcn_mfma_f32_16x16x32_bf16(kf1, qa1, a2, 0, 0, 0);
            float p0 = fexp2(a2[0]);
            float p1 = fexp2(a2[1]);
            float p2 = fexp2(a2[2]);
            float p3 = fexp2(a2[3]);
            rsum += (p0 + p1) + (p2 + p3);
            pk[nt * 2]     = cvt_pk_bf16(p0, p1);
            pk[nt * 2 + 1] = cvt_pk_bf16(p2, p3);
        }

        // ---- P transpose via per-wave LDS: 8x ds_write_b32 (pairs), swizzled ----
        // pk[j] holds keys k0=16*(j>>1)+4*quad+2*(j&1), k0+1 at qrow=m16.
        // store: elem = m16*64 + ((chunk ^ (m16&7))<<3) + pos, chunk=k0>>3, pos=k0&7
        #pragma unroll
        for (int j = 0; j < 8; j++) {
            int chunk = 2 * (j >> 1) + (quad >> 1);
            int pos = (quad & 1) * 4 + 2 * (j & 1);
            *(unsigned*)(pw + m16 * 64 + ((chunk ^ (m16 & 7)) << 3) + pos) = pk[j];
        }

        // ---- P A-frags (per-wave LDS round trip, verified round-0 pattern) ----
        bf16x8 pa0 = *(const bf16x8*)(pw + m16 * 64 + ((quad ^ (m16 & 7)) << 3));
        bf16x8 pa1 = *(const bf16x8*)(pw + m16 * 64 + (((quad + 4) ^ (m16 & 7)) << 3));

        // ---- V frags from LDS + P·V ----
        #pragma unroll
        for (int nt = 0; nt < 4; nt++) {
            int d = nt * 16 + m16;
            bf16x8 vf0 = *(const bf16x8*)(&Vs[buf][d * 64 + ((quad) ^ (d & 7)) * 8]);
            bf16x8 vf1 = *(const bf16x8*)(&Vs[buf][d * 64 + ((quad + 4) ^ (d & 7)) * 8]);
            o[nt] = __builtin_amdgcn_mfma_f32_16x16x32_bf16(pa0, vf0, o[nt], 0, 0, 0);
            o[nt] = __builtin_amdgcn_mfma_f32_16x16x32_bf16(pa1, vf1, o[nt], 0, 0, 0);
        }

        // ---- stage next tile into other buffer; one barrier per tile ----
        if (more) {
            *(bf16x8*)(&Ks[buf ^ 1][soff]) = kst;
            *(bf16x8*)(&Vs[buf ^ 1][soff]) = vst;
        }
        __syncthreads();
    }

    // ---- row-sum: lane holds partial for qrow=m16 over its 16 key-residues; reduce across quads ----
    rsum += __shfl_xor(rsum, 16);
    rsum += __shfl_xor(rsum, 32);

    // ---- normalize + store: o[nt][r] is (qrow=quad*4+r, d=nt*16+m16) ----
    #pragma unroll
    for (int r = 0; r < 4; r++) {
        float inv = 1.0f / __shfl(rsum, quad * 4 + r);
        int n = n0w + quad * 4 + r;
        ushort_t* orow = attn + ((size_t)(b * N_ + n)) * 512 + h * 64 + m16;
        #pragma unroll
        for (int nt = 0; nt < 4; nt++) orow[nt * 16] = f2bf(o[nt][r] * inv);
    }
}

extern "C" void kernel_launch(void* const* d_in, const int* in_sizes, int n_in,
                              void* d_out, int out_size, void* d_ws, size_t ws_size,
                              hipStream_t stream) {
    const float* x     = (const float*)d_in[0];
    const float* gamma = (const float*)d_in[1];
    const float* beta  = (const float*)d_in[2];
    const float* Wqkv  = (const float*)d_in[3];
    const float* Wout  = (const float*)d_in[4];
    const float* bout  = (const float*)d_in[5];
    const float* rel   = (const float*)d_in[6];
    const int*   mask  = (const int*)d_in[7];
    float* out = (float*)d_out;

    char* wsb = (char*)d_ws;
    ushort_t* xn    = (ushort_t*)(wsb);                    //  8 MB
    ushort_t* attnb = (ushort_t*)(wsb + ( 8u << 20));      //  8 MB
    ushort_t* qb    = (ushort_t*)(wsb + (16u << 20));      //  8 MB
    ushort_t* kb    = (ushort_t*)(wsb + (24u << 20));      //  8 MB
    ushort_t* vb    = (ushort_t*)(wsb + (32u << 20));      //  8 MB
    ushort_t* WqkvT = (ushort_t*)(wsb + (40u << 20));      //  1.5 MB
    ushort_t* WoutT = (ushort_t*)(wsb + (42u << 20));      //  0.5 MB
    ushort_t* bp    = (ushort_t*)(wsb + (44u << 20));      //  8 MB

    // 1. fused prep: bias_pack + layernorm + both weight transposes (one launch)
    prep_kernel<<<PREP_BIAS + PREP_LN + PREP_WQ + PREP_WO, 256, 0, stream>>>(
        x, gamma, beta, xn, Wqkv, WqkvT, Wout, WoutT, rel, mask, bp);

    // 2. QKV projection (MFMA + global_load_lds) -> bf16 q(scaled by 0.125*log2e)/k/v
    gemm_qkv<<<dim3(1536 / 128, 8192 / 128), 256, 0, stream>>>(xn, WqkvT, qb, kb, vb);

    // 3. MFMA flash attention v8 -> bf16
    attn_mfma<<<512, 512, 0, stream>>>(qb, kb, vb, bp, attnb);

    // 4. output projection + bias (MFMA + global_load_lds) -> fp32
    gemm_out<<<dim3(512 / 128, 8192 / 64), 256, 0, stream>>>(attnb, WoutT, bout, out);
}

// Round 5
// 188.743 us; speedup vs baseline: 1.1158x; 1.0617x over previous
//
#include <hip/hip_runtime.h>

typedef __attribute__((ext_vector_type(8))) short bf16x8;
typedef __attribute__((ext_vector_type(4))) short bf16x4;
typedef __attribute__((ext_vector_type(4))) float f32x4;
typedef unsigned short ushort_t;

#define B_ 4
#define H_ 8
#define N_ 2048
#define D_ 512
#define MAXREL 199   // MAX_REL-1
#define LOG2E 1.4426950408889634f

__device__ __forceinline__ ushort_t f2bf(float f) {
    union { float f; unsigned u; } v; v.f = f;
    unsigned r = v.u + 0x7fffu + ((v.u >> 16) & 1u);
    return (ushort_t)(r >> 16);
}
__device__ __forceinline__ float bf2f(ushort_t u) {
    union { unsigned u; float f; } v; v.u = ((unsigned)u) << 16;
    return v.f;
}
__device__ __forceinline__ float fexp2(float x) {
#if __has_builtin(__builtin_amdgcn_exp2f)
    return __builtin_amdgcn_exp2f(x);
#else
    return __expf(x * 0.6931471805599453f);
#endif
}
__device__ __forceinline__ unsigned cvt_pk_bf16(float lo, float hi) {
    unsigned r;
    asm("v_cvt_pk_bf16_f32 %0, %1, %2" : "=v"(r) : "v"(lo), "v"(hi));
    return r;
}
// async global->LDS, 16B per lane; lds dest = wave-uniform base + lane*16
__device__ __forceinline__ void gl_lds16(const ushort_t* g, ushort_t* l) {
    __builtin_amdgcn_global_load_lds(
        (const __attribute__((address_space(1))) void*)g,
        (__attribute__((address_space(3))) void*)l,
        16, 0, 0);
}

// ---------------- fused prep: bias_pack | layernorm | wtrans(Wqkv) | wtrans(Wout) ----------------
#define PREP_BIAS  16384                    // (N*N)/256
#define PREP_LN    8192                     // B*N rows
#define PREP_WQ    768                      // (1536/32)*(512/32)
#define PREP_WO    256                      // (512/32)*(512/32)
__global__ __launch_bounds__(256) void prep_kernel(const float* __restrict__ x,
                                                   const float* __restrict__ gamma,
                                                   const float* __restrict__ beta,
                                                   ushort_t* __restrict__ xn,
                                                   const float* __restrict__ Wqkv,
                                                   ushort_t* __restrict__ WqkvT,
                                                   const float* __restrict__ Wout,
                                                   ushort_t* __restrict__ WoutT,
                                                   const float* __restrict__ rel,
                                                   const int* __restrict__ mask,
                                                   ushort_t* __restrict__ bp) {
    __shared__ float smem[32 * 33];
    const int blk = blockIdx.x;
    const int t = threadIdx.x;

    if (blk < PREP_BIAS) {
        // ---- bias+mask pack into attn load order [qt][jt][w][nt][quad][m16][k4], log2 domain ----
        int idx = blk * 256 + t;   // n*2048 + m
        int n = idx >> 11, m = idx & 2047;
        int dl = n - m;
        dl = dl < -MAXREL ? -MAXREL : (dl > MAXREL ? MAXREL : dl);
        float v = (mask[idx] == 0) ? -1e9f : rel[dl + MAXREL] * LOG2E;
        // qrow = qt*128 + w*16 + m16 ; key = jt*64 + nt*16 + quad*4 + k4
        int off = ((n >> 7) << 18) + ((m >> 6) << 13) + (((n >> 4) & 7) << 10)
                + (((m >> 4) & 3) << 8) + (((m >> 2) & 3) << 6) + ((n & 15) << 2) + (m & 3);
        bp[off] = f2bf(v);
    } else if (blk < PREP_BIAS + PREP_LN) {
        // ---- LayerNorm row ----
        const int row = blk - PREP_BIAS;
        const float* xr = x + (size_t)row * D_;
        float v0 = xr[t];
        float v1 = xr[t + 256];
        float s = v0 + v1;
        for (int o = 32; o > 0; o >>= 1) s += __shfl_down(s, o);
        if ((t & 63) == 0) smem[t >> 6] = s;
        __syncthreads();
        float mu = (smem[0] + smem[1] + smem[2] + smem[3]) * (1.0f / D_);
        __syncthreads();
        float d0 = v0 - mu, d1 = v1 - mu;
        float s2 = d0 * d0 + d1 * d1;
        for (int o = 32; o > 0; o >>= 1) s2 += __shfl_down(s2, o);
        if ((t & 63) == 0) smem[t >> 6] = s2;
        __syncthreads();
        float var = (smem[0] + smem[1] + smem[2] + smem[3]) * (1.0f / D_);
        float rs = rsqrtf(var + 1e-5f);
        ushort_t* yr = xn + (size_t)row * D_;
        yr[t]       = f2bf(d0 * rs * gamma[t]       + beta[t]);
        yr[t + 256] = f2bf(d1 * rs * gamma[t + 256] + beta[t + 256]);
    } else {
        // ---- weight transpose fp32 [K][Nn] -> bf16 [Nn][K] ----
        const float* W; ushort_t* Wt; int Nn, i;
        if (blk < PREP_BIAS + PREP_LN + PREP_WQ) {
            i = blk - (PREP_BIAS + PREP_LN); W = Wqkv; Wt = WqkvT; Nn = 1536;
        } else {
            i = blk - (PREP_BIAS + PREP_LN + PREP_WQ); W = Wout; Wt = WoutT; Nn = 512;
        }
        const int nb = Nn >> 5;
        const int bx = (i % nb) * 32, by = (i / nb) * 32;
        const int tx = t & 31, ty = t >> 5;
        float (*tile)[33] = (float(*)[33])smem;
        #pragma unroll
        for (int k = 0; k < 32; k += 8)
            tile[ty + k][tx] = W[(size_t)(by + ty + k) * Nn + bx + tx];
        __syncthreads();
        #pragma unroll
        for (int k = 0; k < 32; k += 8)
            Wt[(size_t)(bx + ty + k) * 512 + by + tx] = f2bf(tile[tx][ty + k]);
    }
}

// ---------------- QKV GEMM (MFMA bf16, global_load_lds staging): q scaled by 0.125*log2e ----------------
__global__ __launch_bounds__(256) void gemm_qkv(const ushort_t* __restrict__ A,
                                                const ushort_t* __restrict__ Bt,
                                                ushort_t* __restrict__ qb,
                                                ushort_t* __restrict__ kb,
                                                ushort_t* __restrict__ vb) {
    __shared__ ushort_t As[128 * 32];
    __shared__ ushort_t Bs[128 * 32];
    const int t = threadIdx.x;
    const int lane = t & 63, w = t >> 6;
    const int m16 = lane & 15, quad = lane >> 4;
    const int wr = w >> 1, wc = w & 1;
    const int r0 = blockIdx.y * 128, c0 = blockIdx.x * 128;

    const ushort_t* Ag = A  + (size_t)(r0 + (t >> 2)) * D_ + (t & 3) * 8;
    const ushort_t* Bg = Bt + (size_t)(c0 + (t >> 2)) * D_ + (t & 3) * 8;
    ushort_t* AsW = As + w * 512;
    ushort_t* BsW = Bs + w * 512;

    f32x4 acc[4][4];
    #pragma unroll
    for (int i = 0; i < 4; i++)
        #pragma unroll
        for (int j = 0; j < 4; j++) acc[i][j] = (f32x4){0.f, 0.f, 0.f, 0.f};

    for (int k0 = 0; k0 < D_; k0 += 32) {
        gl_lds16(Ag + k0, AsW);
        gl_lds16(Ag + k0 + (size_t)64 * D_, AsW + 2048);
        gl_lds16(Bg + k0, BsW);
        gl_lds16(Bg + k0 + (size_t)64 * D_, BsW + 2048);
        __syncthreads();
        bf16x8 af[4], bfr[4];
        #pragma unroll
        for (int rt = 0; rt < 4; rt++)
            af[rt] = *(const bf16x8*)(As + (wr * 64 + rt * 16 + m16) * 32 + quad * 8);
        #pragma unroll
        for (int ct = 0; ct < 4; ct++)
            bfr[ct] = *(const bf16x8*)(Bs + (wc * 64 + ct * 16 + m16) * 32 + quad * 8);
        #pragma unroll
        for (int rt = 0; rt < 4; rt++)
            #pragma unroll
            for (int ct = 0; ct < 4; ct++)
                acc[rt][ct] = __builtin_amdgcn_mfma_f32_16x16x32_bf16(af[rt], bfr[ct], acc[rt][ct], 0, 0, 0);
        __syncthreads();
    }

    #pragma unroll
    for (int ct = 0; ct < 4; ct++) {
        int cc = c0 + wc * 64 + ct * 16;      // 16-aligned, uniform per ct
        int which = cc >> 9;
        int h = (cc >> 6) & 7;
        int d = (cc & 63) + m16;
        #pragma unroll
        for (int rt = 0; rt < 4; rt++) {
            int rowb = r0 + wr * 64 + rt * 16 + quad * 4;
            int b = rowb >> 11, n0 = rowb & 2047;
            if (which == 0) {
                #pragma unroll
                for (int r = 0; r < 4; r++)
                    qb[((size_t)((b * H_ + h) * N_ + n0 + r)) * 64 + d] = f2bf(acc[rt][ct][r] * (0.125f * LOG2E));
            } else if (which == 1) {
                #pragma unroll
                for (int r = 0; r < 4; r++)
                    kb[((size_t)((b * H_ + h) * N_ + n0 + r)) * 64 + d] = f2bf(acc[rt][ct][r]);
            } else {
                union { ushort_t u4[4]; unsigned long long ll; } pk;
                #pragma unroll
                for (int r = 0; r < 4; r++) pk.u4[r] = f2bf(acc[rt][ct][r]);
                *(unsigned long long*)(vb + ((size_t)((b * H_ + h) * 64 + d)) * N_ + n0) = pk.ll;
            }
        }
    }
}

// ---------------- Out-proj (MFMA bf16, global_load_lds, BM=64) ----------------
__global__ __launch_bounds__(256) void gemm_out(const ushort_t* __restrict__ A,
                                                const ushort_t* __restrict__ Bt,
                                                const float* __restrict__ bias,
                                                float* __restrict__ C) {
    __shared__ ushort_t As[64 * 32];
    __shared__ ushort_t Bs[128 * 32];
    const int t = threadIdx.x;
    const int lane = t & 63, w = t >> 6;
    const int m16 = lane & 15, quad = lane >> 4;
    const int wr = w >> 1, wc = w & 1;        // wave tile: 32 rows x 64 cols
    const int r0 = blockIdx.y * 64, c0 = blockIdx.x * 128;

    const ushort_t* Ag = A  + (size_t)(r0 + (t >> 2)) * D_ + (t & 3) * 8;
    const ushort_t* Bg = Bt + (size_t)(c0 + (t >> 2)) * D_ + (t & 3) * 8;
    ushort_t* AsW = As + w * 512;
    ushort_t* BsW = Bs + w * 512;

    f32x4 acc[2][4];
    #pragma unroll
    for (int i = 0; i < 2; i++)
        #pragma unroll
        for (int j = 0; j < 4; j++) acc[i][j] = (f32x4){0.f, 0.f, 0.f, 0.f};

    for (int k0 = 0; k0 < D_; k0 += 32) {
        gl_lds16(Ag + k0, AsW);
        gl_lds16(Bg + k0, BsW);
        gl_lds16(Bg + k0 + (size_t)64 * D_, BsW + 2048);
        __syncthreads();
        bf16x8 af[2], bfr[4];
        #pragma unroll
        for (int mf = 0; mf < 2; mf++)
            af[mf] = *(const bf16x8*)(As + (wr * 32 + mf * 16 + m16) * 32 + quad * 8);
        #pragma unroll
        for (int nt = 0; nt < 4; nt++)
            bfr[nt] = *(const bf16x8*)(Bs + (wc * 64 + nt * 16 + m16) * 32 + quad * 8);
        #pragma unroll
        for (int mf = 0; mf < 2; mf++)
            #pragma unroll
            for (int nt = 0; nt < 4; nt++)
                acc[mf][nt] = __builtin_amdgcn_mfma_f32_16x16x32_bf16(af[mf], bfr[nt], acc[mf][nt], 0, 0, 0);
        __syncthreads();
    }

    #pragma unroll
    for (int mf = 0; mf < 2; mf++) {
        #pragma unroll
        for (int nt = 0; nt < 4; nt++) {
            int col = c0 + wc * 64 + nt * 16 + m16;
            int row0 = r0 + wr * 32 + mf * 16 + quad * 4;
            float bv = bias[col];
            #pragma unroll
            for (int r = 0; r < 4; r++)
                C[(size_t)(row0 + r) * 512 + col] = acc[mf][nt][r] + bv;
        }
    }
}

// ---------------- MFMA flash attention v10: v8 + deep pipeline ----------------
// v8 verified core (swapped QK^T, bias-as-acc-init in log2 domain, cvt_pk pack, b64 p_s
// round trip, scalar rsum) + latency fixes: bias prefetched 1 tile ahead in regs, K/V
// staged 2 tiles ahead in regs (static 2x-unrolled loop, no runtime reg indexing),
// s_setprio(1) around both MFMA clusters.
#define ATTN_TILE(JT, KCUR, VCUR, KNXT, VNXT, BCUR, BNXT)                              \
  {                                                                                    \
    const int jt = (JT);                                                               \
    const int buf = jt & 1;                                                            \
    if (jt + 2 < 32) {                                                                 \
      KNXT = *(const bf16x8*)(kgbase + (size_t)((jt + 2) * 64 + srow) * 64 + scb * 8); \
      VNXT = *(const bf16x8*)(vgbase + (size_t)srow * N_ + (jt + 2) * 64 + scb * 8);   \
    }                                                                                  \
    if (jt + 1 < 32) {                                                                 \
      _Pragma("unroll")                                                                \
      for (int nt = 0; nt < 4; nt++)                                                   \
        BNXT[nt] = *(const bf16x4*)(bpb + ((jt + 1) << 13) + (nt << 8));               \
    }                                                                                  \
    unsigned pk[8];                                                                    \
    __builtin_amdgcn_s_setprio(1);                                                     \
    _Pragma("unroll")                                                                  \
    for (int nt = 0; nt < 4; nt++) {                                                   \
      f32x4 a2;                                                                        \
      _Pragma("unroll")                                                                \
      for (int r = 0; r < 4; r++) a2[r] = bf2f((ushort_t)BCUR[nt][r]);                 \
      int kr = nt * 16 + m16;                                                          \
      bf16x8 kf0 = *(const bf16x8*)(&Ks[buf][kr * 64 + ((quad) ^ (kr & 7)) * 8]);      \
      bf16x8 kf1 = *(const bf16x8*)(&Ks[buf][kr * 64 + ((quad + 4) ^ (kr & 7)) * 8]);  \
      a2 = __builtin_amdgcn_mfma_f32_16x16x32_bf16(kf0, qa0, a2, 0, 0, 0);             \
      a2 = __builtin_amdgcn_mfma_f32_16x16x32_bf16(kf1, qa1, a2, 0, 0, 0);             \
      float p0 = fexp2(a2[0]), p1 = fexp2(a2[1]);                                      \
      float p2 = fexp2(a2[2]), p3 = fexp2(a2[3]);                                      \
      rsum += (p0 + p1) + (p2 + p3);                                                   \
      pk[nt * 2]     = cvt_pk_bf16(p0, p1);                                            \
      pk[nt * 2 + 1] = cvt_pk_bf16(p2, p3);                                            \
    }                                                                                  \
    __builtin_amdgcn_s_setprio(0);                                                     \
    _Pragma("unroll")                                                                  \
    for (int i = 0; i < 4; i++) {                                                      \
      int chunk = 2 * i + (quad >> 1);                                                 \
      union { unsigned uu[2]; unsigned long long ll; } wrp;                            \
      wrp.uu[0] = pk[2 * i]; wrp.uu[1] = pk[2 * i + 1];                                \
      *(unsigned long long*)(pw + m16 * 64 + ((chunk ^ (m16 & 7)) << 3)                \
                             + (quad & 1) * 4) = wrp.ll;                               \
    }                                                                                  \
    bf16x8 pa0 = *(const bf16x8*)(pw + m16 * 64 + ((quad ^ (m16 & 7)) << 3));          \
    bf16x8 pa1 = *(const bf16x8*)(pw + m16 * 64 + (((quad + 4) ^ (m16 & 7)) << 3));    \
    __builtin_amdgcn_s_setprio(1);                                                     \
    _Pragma("unroll")                                                                  \
    for (int nt = 0; nt < 4; nt++) {                                                   \
      int d = nt * 16 + m16;                                                           \
      bf16x8 vf0 = *(const bf16x8*)(&Vs[buf][d * 64 + ((quad) ^ (d & 7)) * 8]);        \
      bf16x8 vf1 = *(const bf16x8*)(&Vs[buf][d * 64 + ((quad + 4) ^ (d & 7)) * 8]);    \
      o[nt] = __builtin_amdgcn_mfma_f32_16x16x32_bf16(pa0, vf0, o[nt], 0, 0, 0);       \
      o[nt] = __builtin_amdgcn_mfma_f32_16x16x32_bf16(pa1, vf1, o[nt], 0, 0, 0);       \
    }                                                                                  \
    __builtin_amdgcn_s_setprio(0);                                                     \
    if (jt + 1 < 32) {                                                                 \
      *(bf16x8*)(&Ks[buf ^ 1][soff]) = KCUR;                                           \
      *(bf16x8*)(&Vs[buf ^ 1][soff]) = VCUR;                                           \
    }                                                                                  \
    __syncthreads();                                                                   \
  }

__global__ __launch_bounds__(512, 4) void attn_mfma(const ushort_t* __restrict__ qb,
                                                    const ushort_t* __restrict__ kb,
                                                    const ushort_t* __restrict__ vb,
                                                    const ushort_t* __restrict__ bp,
                                                    ushort_t* __restrict__ attn) {
    __shared__ ushort_t Ks[2][64 * 64];      // [buf][key][d] swizzled, 8KB each
    __shared__ ushort_t Vs[2][64 * 64];      // [buf][d][key] swizzled, 8KB each
    __shared__ ushort_t p_s[8][16 * 64];     // [wave][qrow][key] swizzled, 16KB

    const int t = threadIdx.x;
    const int w = t >> 6, lane = t & 63;
    const int m16 = lane & 15, quad = lane >> 4;
    const int id = blockIdx.x;
    const int bh = id & 31;                  // XCD = id%8 = bh%8 (heuristic)
    const int qt = id >> 5;
    const int b = bh >> 3, h = bh & 7;
    const int n0w = qt * 128 + w * 16;

    // staging: thread stages exactly one 8-elem chunk of K and of V per tile
    const int srow = t >> 3, scb = t & 7;
    const int soff = srow * 64 + (scb ^ (srow & 7)) * 8;
    const ushort_t* kgbase = kb + ((size_t)bh * N_) * 64;   // [key][d]
    const ushort_t* vgbase = vb + ((size_t)bh * 64) * N_;   // [d][key]

    // Q frags (one 16-row m-frag per wave)
    const ushort_t* qpb = qb + ((size_t)(bh * N_ + n0w + m16)) * 64 + quad * 8;
    bf16x8 qa0 = *(const bf16x8*)(qpb);
    bf16x8 qa1 = *(const bf16x8*)(qpb + 32);

    // bias packed [qt][jt][w][nt][quad][m16][k4]; per phase the 16 m16-lanes read 128B contiguous
    const ushort_t* bpb = bp + ((size_t)qt << 18) + (w << 10) + (quad << 6) + (m16 << 2);

    // prologue: stage tile 0 into buf 0; prefetch tile 1 (regs) and bias jt=0 (regs)
    *(bf16x8*)(&Ks[0][soff]) = *(const bf16x8*)(kgbase + (size_t)srow * 64 + scb * 8);
    *(bf16x8*)(&Vs[0][soff]) = *(const bf16x8*)(vgbase + (size_t)srow * N_ + scb * 8);
    bf16x8 kA = *(const bf16x8*)(kgbase + (size_t)(64 + srow) * 64 + scb * 8);
    bf16x8 vA = *(const bf16x8*)(vgbase + (size_t)srow * N_ + 64 + scb * 8);
    bf16x8 kB, vB;
    bf16x4 bA[4], bB[4];
    #pragma unroll
    for (int nt = 0; nt < 4; nt++) bA[nt] = *(const bf16x4*)(bpb + (nt << 8));
    __syncthreads();

    f32x4 o[4];
    #pragma unroll
    for (int nt = 0; nt < 4; nt++) o[nt] = (f32x4){0.f, 0.f, 0.f, 0.f};
    float rsum = 0.f;

    ushort_t* pw = p_s[w];

    for (int jt2 = 0; jt2 < 16; jt2++) {
        ATTN_TILE(2 * jt2,     kA, vA, kB, vB, bA, bB);
        ATTN_TILE(2 * jt2 + 1, kB, vB, kA, vA, bB, bA);
    }

    // ---- row-sum: lane holds partial for qrow=m16 over its 16 key-residues; reduce across quads ----
    rsum += __shfl_xor(rsum, 16);
    rsum += __shfl_xor(rsum, 32);

    // ---- normalize + store: o[nt][r] is (qrow=quad*4+r, d=nt*16+m16) ----
    #pragma unroll
    for (int r = 0; r < 4; r++) {
        float inv = 1.0f / __shfl(rsum, quad * 4 + r);
        int n = n0w + quad * 4 + r;
        ushort_t* orow = attn + ((size_t)(b * N_ + n)) * 512 + h * 64 + m16;
        #pragma unroll
        for (int nt = 0; nt < 4; nt++) orow[nt * 16] = f2bf(o[nt][r] * inv);
    }
}

extern "C" void kernel_launch(void* const* d_in, const int* in_sizes, int n_in,
                              void* d_out, int out_size, void* d_ws, size_t ws_size,
                              hipStream_t stream) {
    const float* x     = (const float*)d_in[0];
    const float* gamma = (const float*)d_in[1];
    const float* beta  = (const float*)d_in[2];
    const float* Wqkv  = (const float*)d_in[3];
    const float* Wout  = (const float*)d_in[4];
    const float* bout  = (const float*)d_in[5];
    const float* rel   = (const float*)d_in[6];
    const int*   mask  = (const int*)d_in[7];
    float* out = (float*)d_out;

    char* wsb = (char*)d_ws;
    ushort_t* xn    = (ushort_t*)(wsb);                    //  8 MB
    ushort_t* attnb = (ushort_t*)(wsb + ( 8u << 20));      //  8 MB
    ushort_t* qb    = (ushort_t*)(wsb + (16u << 20));      //  8 MB
    ushort_t* kb    = (ushort_t*)(wsb + (24u << 20));      //  8 MB
    ushort_t* vb    = (ushort_t*)(wsb + (32u << 20));      //  8 MB
    ushort_t* WqkvT = (ushort_t*)(wsb + (40u << 20));      //  1.5 MB
    ushort_t* WoutT = (ushort_t*)(wsb + (42u << 20));      //  0.5 MB
    ushort_t* bp    = (ushort_t*)(wsb + (44u << 20));      //  8 MB

    // 1. fused prep: bias_pack + layernorm + both weight transposes (one launch)
    prep_kernel<<<PREP_BIAS + PREP_LN + PREP_WQ + PREP_WO, 256, 0, stream>>>(
        x, gamma, beta, xn, Wqkv, WqkvT, Wout, WoutT, rel, mask, bp);

    // 2. QKV projection (MFMA + global_load_lds) -> bf16 q(scaled by 0.125*log2e)/k/v
    gemm_qkv<<<dim3(1536 / 128, 8192 / 128), 256, 0, stream>>>(xn, WqkvT, qb, kb, vb);

    // 3. MFMA flash attention v10 -> bf16
    attn_mfma<<<512, 512, 0, stream>>>(qb, kb, vb, bp, attnb);

    // 4. output projection + bias (MFMA + global_load_lds) -> fp32
    gemm_out<<<dim3(512 / 128, 8192 / 64), 256, 0, stream>>>(attnb, WoutT, bout, out);
}